// Round 7
// baseline (1546.076 us; speedup 1.0000x reference)
//
#include <hip/hip_runtime.h>
#include <math.h>

#define Bn   16
#define Nn   4096
#define Cn   64
#define Mn   1024
#define Kn   32
#define OUTn 128
#define EPS  1e-5f

typedef unsigned long long u64;
typedef unsigned int u32;

__device__ __forceinline__ u64 u64min(u64 a, u64 b) { return a < b ? a : b; }
__device__ __forceinline__ u64 u64max(u64 a, u64 b) { return a > b ? a : b; }

// DPP move of a u64 (2x i32 update_dpp). old = x -> invalid/masked lanes keep x,
// the identity for both max and min combines.
template<int CTRL>
__device__ __forceinline__ u64 dpp_u64(u64 x) {
  union { u64 q; u32 w[2]; } in, out;
  in.q = x;
  out.w[0] = (u32)__builtin_amdgcn_update_dpp((int)in.w[0], (int)in.w[0], CTRL, 0xf, 0xf, false);
  out.w[1] = (u32)__builtin_amdgcn_update_dpp((int)in.w[1], (int)in.w[1], CTRL, 0xf, 0xf, false);
  return out.q;
}

// Canonical GCN wave64 reduce: row_shr 1,2,4,8 -> bcast15 -> bcast31.
// Result valid in lane 63 only. Pure VALU.
__device__ __forceinline__ u64 wave_max_dpp(u64 v) {
  v = u64max(v, dpp_u64<0x111>(v));
  v = u64max(v, dpp_u64<0x112>(v));
  v = u64max(v, dpp_u64<0x114>(v));
  v = u64max(v, dpp_u64<0x118>(v));
  v = u64max(v, dpp_u64<0x142>(v));
  v = u64max(v, dpp_u64<0x143>(v));
  return v;
}
__device__ __forceinline__ u64 wave_min_dpp(u64 v) {
  v = u64min(v, dpp_u64<0x111>(v));
  v = u64min(v, dpp_u64<0x112>(v));
  v = u64min(v, dpp_u64<0x114>(v));
  v = u64min(v, dpp_u64<0x118>(v));
  v = u64min(v, dpp_u64<0x142>(v));
  v = u64min(v, dpp_u64<0x143>(v));
  return v;
}

// ---------------------------------------------------------------------------
// FPS: one block/batch, 256 threads, 16 pts/thread in regs.
// Packed keys: (bits(d)<<32)|~n ; u64 MAX == (max d, tie -> lowest n).
// BARRIER-FREE cross-wave combine: lane63 of each wave writes its partial to
// part[m&1][wid], threadfence, LDS atomicAdd on an accumulating counter; all
// waves spin until cnt >= 4*m, then independently combine 4 partials + read
// centroid. Waves skew <= 1 step (inc happens only after reading previous
// partials), so 2 parity slots suffice. Single workgroup -> co-resident, safe.
// ---------------------------------------------------------------------------
__global__ __launch_bounds__(256) void fps_kernel(
    const float* __restrict__ xyz, float* __restrict__ cent)
{
  __shared__ float4 pts4[Nn];          // 64 KB
  __shared__ __align__(16) u64 part[2][4];
  __shared__ int cnt;

  const int b = blockIdx.x;
  const int t = threadIdx.x;
  const float* src = xyz + (size_t)b * Nn * 3;

  if (t == 0) cnt = 0;
  for (int i = t; i < Nn; i += 256) {
    pts4[i] = make_float4(src[3*i+0], src[3*i+1], src[3*i+2], 0.0f);
  }
  __syncthreads();

  const float4 c0 = pts4[0];

  float px[16], py[16], pz[16], d[16];
  u32 ninv[16];
#pragma unroll
  for (int j = 0; j < 16; ++j) {
    const int n = j * 256 + t;
    ninv[j] = (u32)(~n);
    const float4 p = pts4[n];
    px[j] = p.x; py[j] = p.y; pz[j] = p.z;
    const float dx = px[j] - c0.x, dy = py[j] - c0.y, dz = pz[j] - c0.z;
    d[j] = (dx * dx + dy * dy) + dz * dz;
  }

  if (t == 0) {
    float* o = cent + (size_t)b * Mn * 3;
    o[0] = c0.x; o[1] = c0.y; o[2] = c0.z;
  }

  for (int m = 1; m < Mn; ++m) {
    // pack + depth-4 tree max (keys are register pairs; pack is free)
    u64 k[16];
#pragma unroll
    for (int j = 0; j < 16; ++j)
      k[j] = ((u64)__float_as_uint(d[j]) << 32) | ninv[j];
#pragma unroll
    for (int st = 1; st < 16; st <<= 1)
#pragma unroll
      for (int j = 0; j < 16; j += (st << 1))
        k[j] = u64max(k[j], k[j + st]);

    const u64 bk = wave_max_dpp(k[0]);
    const int par = m & 1;
    if ((t & 63) == 63) {
      part[par][t >> 6] = bk;
      __threadfence_block();             // partial visible before count
      atomicAdd(&cnt, 1);
    }
    while (__hip_atomic_load(&cnt, __ATOMIC_RELAXED,
                             __HIP_MEMORY_SCOPE_WORKGROUP) < 4 * m) {}
    __threadfence_block();

    const u64 f = u64max(u64max(part[par][0], part[par][1]),
                         u64max(part[par][2], part[par][3]));
    const int fi = (int)(~(u32)f);      // low word was ~n

    const float4 cp = pts4[fi];
    if (t == 0) {
      float* o = cent + ((size_t)b * Mn + m) * 3;
      o[0] = cp.x; o[1] = cp.y; o[2] = cp.z;
    }

#pragma unroll
    for (int j = 0; j < 16; ++j) {
      const float dx = px[j] - cp.x, dy = py[j] - cp.y, dz = pz[j] - cp.z;
      const float nd = (dx * dx + dy * dy) + dz * dz;
      d[j] = fminf(d[j], nd);
    }
  }
}

// ---------------------------------------------------------------------------
// KNN: ONE WAVE per centroid (4 centroids/block), zero barriers, zero LDS.
// 64 pts/lane as 4 register groups of 16 u64 keys + cached group minima.
// Key = (mono(bits(d2))<<32)|n ; u64 MIN == (min d2, tie -> lowest idx)
// == stable top_k set. Point n = grp*1024 + j*64 + lane.
// Per step: DPP wave-min -> readlane broadcast; unique owner lane invalidates
// one key and rescans only its group (uniform group -> scalar branch).
// d2 uses the exact reference formula (cc+pp)-2*dot in f32.
// ---------------------------------------------------------------------------
__global__ __launch_bounds__(256) void knn_kernel(
    const float* __restrict__ xyz, const float* __restrict__ cent,
    int* __restrict__ osel)
{
  const int t    = threadIdx.x;
  const int lane = t & 63;
  const int wid  = __builtin_amdgcn_readfirstlane(t >> 6);
  const int g    = (blockIdx.x << 2) + wid;      // centroid id
  const int b    = g >> 10;
  const float* P = xyz + (size_t)b * Nn * 3;

  const float cx = cent[(size_t)g * 3 + 0];
  const float cy = cent[(size_t)g * 3 + 1];
  const float cz = cent[(size_t)g * 3 + 2];
  const float cc2 = (cx * cx + cy * cy) + cz * cz;

  u64 kk[4][16];                 // all indices compile-time (unrolled)
  u64 gm0, gm1, gm2, gm3;

#pragma unroll
  for (int grp = 0; grp < 4; ++grp) {
#pragma unroll
    for (int j = 0; j < 16; ++j) {
      const int n = grp * 1024 + j * 64 + lane;
      const float x = P[n*3+0], y = P[n*3+1], z = P[n*3+2];
      const float pp = (x * x + y * y) + z * z;
      const float dt = (cx * x + cy * y) + cz * z;
      const float d2 = (cc2 + pp) - 2.0f * dt;
      const u32 bu = __float_as_uint(d2);
      const u32 mo = bu ^ (0x80000000u | (u32)((int)bu >> 31)); // order-preserving
      kk[grp][j] = ((u64)mo << 32) | (u32)n;
    }
  }
#define TREE16(dst, A)                                                  \
  {                                                                     \
    u64 t0 = u64min(A[0], A[1]),  t1 = u64min(A[2], A[3]);              \
    u64 t2 = u64min(A[4], A[5]),  t3 = u64min(A[6], A[7]);              \
    u64 t4 = u64min(A[8], A[9]),  t5 = u64min(A[10], A[11]);            \
    u64 t6 = u64min(A[12], A[13]), t7 = u64min(A[14], A[15]);           \
    t0 = u64min(t0, t1); t2 = u64min(t2, t3);                           \
    t4 = u64min(t4, t5); t6 = u64min(t6, t7);                           \
    dst = u64min(u64min(t0, t2), u64min(t4, t6));                       \
  }
  TREE16(gm0, kk[0]); TREE16(gm1, kk[1]);
  TREE16(gm2, kk[2]); TREE16(gm3, kk[3]);
  u64 bk = u64min(u64min(gm0, gm1), u64min(gm2, gm3));

  int myfi = 0;
  for (int s = 0; s < Kn; ++s) {
    const u64 v = wave_min_dpp(bk);
    const u32 flo = (u32)__builtin_amdgcn_readlane((int)(u32)v, 63);
    const u32 fhi = (u32)__builtin_amdgcn_readlane((int)(u32)(v >> 32), 63);
    const u64 f = ((u64)fhi << 32) | flo;
    const int fi = (int)flo;                       // point index (uniform)
    if (lane == s) myfi = fi;

    const int og = __builtin_amdgcn_readfirstlane(fi >> 10);       // group
    const int oj = __builtin_amdgcn_readfirstlane((fi >> 6) & 15); // slot
    if (lane == (fi & 63)) {                       // unique owner lane
#pragma unroll
      for (int grp = 0; grp < 4; ++grp) {
        if (grp == og) {                           // uniform (scalar) branch
#pragma unroll
          for (int j = 0; j < 16; ++j)
            if (j == oj) kk[grp][j] = ~0ull;
          u64 nm;
          TREE16(nm, kk[grp]);
          if (grp == 0) gm0 = nm;
          else if (grp == 1) gm1 = nm;
          else if (grp == 2) gm2 = nm;
          else gm3 = nm;
        }
      }
      bk = u64min(u64min(gm0, gm1), u64min(gm2, gm3));
    }
    (void)f;
  }
#undef TREE16

  if (lane < Kn) osel[(size_t)g * 128 + lane] = myfi;
}

// ---------------------------------------------------------------------------
// MLP: one block (256 thr) per 4 centroids = 128 rows. (unchanged)
// ---------------------------------------------------------------------------
__global__ __launch_bounds__(256) void mlp_kernel(
    const float* __restrict__ xyz, const float* __restrict__ feat,
    const float* __restrict__ W1, const float* __restrict__ b1,
    const float* __restrict__ g1, const float* __restrict__ be1,
    const float* __restrict__ W2, const float* __restrict__ b2,
    const float* __restrict__ g2, const float* __restrict__ be2,
    const float* __restrict__ Wout, const float* __restrict__ bout,
    const float* __restrict__ cent, float* __restrict__ out)
{
  __shared__ float A[128][68];
  __shared__ float lnS[2][128];
  __shared__ float lnQ[2][128];

  const int bm0 = blockIdx.x << 2;
  const int b   = bm0 >> 10;
  const int t   = threadIdx.x;
  const int wid = __builtin_amdgcn_readfirstlane(t >> 6);
  const int lane = t & 63;

  const float* F = feat + (size_t)b * Nn * Cn;
  const float* P = xyz  + (size_t)b * Nn * 3;
  const int* osel = (const int*)out;

  // ---- gather: 2 threads per row ----
  {
    const int row = t >> 1, half = t & 1;
    const int g = bm0 + (row >> 5);
    const int n = osel[(size_t)g * 128 + (row & 31)];
    const float4* f4 = (const float4*)(F + (size_t)n * Cn + half * 32);
#pragma unroll
    for (int q = 0; q < 8; ++q)
      *(float4*)&A[row][half * 32 + q * 4] = f4[q];
    if (half) {
      A[row][64] = P[n*3+0] - cent[(size_t)g*3+0];
      A[row][65] = P[n*3+1] - cent[(size_t)g*3+1];
      A[row][66] = P[n*3+2] - cent[(size_t)g*3+2];
      A[row][67] = 0.0f;
    }
  }
  __syncthreads();

  const int row = ((wid & 1) << 6) + lane;
  const int c0  = (wid >> 1) << 5;
  const int slot = wid >> 1;

  float acc[32];

  // ---- layer 1 (K=67) ----
  {
    const float* w1b = W1 + (size_t)c0 * 67;
#pragma unroll
    for (int cc = 0; cc < 32; ++cc) acc[cc] = b1[c0 + cc];
    for (int k4 = 0; k4 < 16; ++k4) {
      const float4 xv = *(const float4*)&A[row][k4 * 4];
#pragma unroll
      for (int cc = 0; cc < 32; ++cc) {
        const float* w = w1b + cc * 67 + k4 * 4 + 3;
        acc[cc] = fmaf(xv.x, w[0], acc[cc]);
        acc[cc] = fmaf(xv.y, w[1], acc[cc]);
        acc[cc] = fmaf(xv.z, w[2], acc[cc]);
        acc[cc] = fmaf(xv.w, w[3], acc[cc]);
      }
    }
    const float x0 = A[row][64], x1 = A[row][65], x2 = A[row][66];
#pragma unroll
    for (int cc = 0; cc < 32; ++cc) {
      const float* w = w1b + cc * 67;
      acc[cc] = fmaf(x0, w[0], acc[cc]);
      acc[cc] = fmaf(x1, w[1], acc[cc]);
      acc[cc] = fmaf(x2, w[2], acc[cc]);
    }
  }

  // ---- LN1 + ReLU -> A ----
  {
    float s = 0.0f, q = 0.0f;
#pragma unroll
    for (int cc = 0; cc < 32; ++cc) { s += acc[cc]; q = fmaf(acc[cc], acc[cc], q); }
    lnS[slot][row] = s; lnQ[slot][row] = q;
    __syncthreads();
    const float st = s + lnS[slot ^ 1][row];
    const float qt = q + lnQ[slot ^ 1][row];
    const float mu = st * 0.015625f;
    const float var = qt * 0.015625f - mu * mu;
    const float rs = rsqrtf(var + EPS);
#pragma unroll
    for (int cc = 0; cc < 32; ++cc) {
      const float y = (acc[cc] - mu) * rs * g1[c0 + cc] + be1[c0 + cc];
      acc[cc] = fmaxf(y, 0.0f);
    }
#pragma unroll
    for (int c4 = 0; c4 < 8; ++c4)
      *(float4*)&A[row][c0 + c4 * 4] =
          make_float4(acc[c4*4], acc[c4*4+1], acc[c4*4+2], acc[c4*4+3]);
  }
  __syncthreads();

  // ---- layer 2 (K=64) ----
  {
    const float* w2b = W2 + (size_t)c0 * 64;
    float a2[32];
#pragma unroll
    for (int cc = 0; cc < 32; ++cc) a2[cc] = b2[c0 + cc];
    for (int k4 = 0; k4 < 16; ++k4) {
      const float4 xv = *(const float4*)&A[row][k4 * 4];
#pragma unroll
      for (int cc = 0; cc < 32; ++cc) {
        const float* w = w2b + cc * 64 + k4 * 4;
        a2[cc] = fmaf(xv.x, w[0], a2[cc]);
        a2[cc] = fmaf(xv.y, w[1], a2[cc]);
        a2[cc] = fmaf(xv.z, w[2], a2[cc]);
        a2[cc] = fmaf(xv.w, w[3], a2[cc]);
      }
    }
#pragma unroll
    for (int cc = 0; cc < 32; ++cc) acc[cc] = a2[cc];
  }

  // ---- LN2 + ReLU -> A ----
  {
    float s = 0.0f, q = 0.0f;
#pragma unroll
    for (int cc = 0; cc < 32; ++cc) { s += acc[cc]; q = fmaf(acc[cc], acc[cc], q); }
    lnS[slot][row] = s; lnQ[slot][row] = q;
    __syncthreads();
    const float st = s + lnS[slot ^ 1][row];
    const float qt = q + lnQ[slot ^ 1][row];
    const float mu = st * 0.015625f;
    const float var = qt * 0.015625f - mu * mu;
    const float rs = rsqrtf(var + EPS);
#pragma unroll
    for (int cc = 0; cc < 32; ++cc) {
      const float y = (acc[cc] - mu) * rs * g2[c0 + cc] + be2[c0 + cc];
      acc[cc] = fmaxf(y, 0.0f);
    }
#pragma unroll
    for (int c4 = 0; c4 < 8; ++c4)
      *(float4*)&A[row][c0 + c4 * 4] =
          make_float4(acc[c4*4], acc[c4*4+1], acc[c4*4+2], acc[c4*4+3]);
  }
  __syncthreads();

  // ---- layer 3 (K=64, 64 cols/wave) + maxpool + store ----
  {
    const int c03 = (wid >> 1) << 6;
    const float* w3b = Wout + (size_t)c03 * 64;
    float a3[64];
#pragma unroll
    for (int cc = 0; cc < 64; ++cc) a3[cc] = bout[c03 + cc];
    for (int k4 = 0; k4 < 16; ++k4) {
      const float4 xv = *(const float4*)&A[row][k4 * 4];
#pragma unroll
      for (int cc = 0; cc < 64; ++cc) {
        const float* w = w3b + cc * 64 + k4 * 4;
        a3[cc] = fmaf(xv.x, w[0], a3[cc]);
        a3[cc] = fmaf(xv.y, w[1], a3[cc]);
        a3[cc] = fmaf(xv.z, w[2], a3[cc]);
        a3[cc] = fmaf(xv.w, w[3], a3[cc]);
      }
    }
#pragma unroll
    for (int cc = 0; cc < 64; ++cc) {
      float v = a3[cc];
      v = fmaxf(v, __shfl_xor(v, 1));
      v = fmaxf(v, __shfl_xor(v, 2));
      v = fmaxf(v, __shfl_xor(v, 4));
      v = fmaxf(v, __shfl_xor(v, 8));
      v = fmaxf(v, __shfl_xor(v, 16));
      a3[cc] = v;
    }
    const int g = bm0 + ((wid & 1) << 1) + (lane >> 5);
    float* og = out + (size_t)g * OUTn + c03;
#pragma unroll
    for (int cc = 0; cc < 64; ++cc)
      if ((lane & 31) == (cc & 31)) og[cc] = a3[cc];
  }
}

// ---------------------------------------------------------------------------
extern "C" void kernel_launch(void* const* d_in, const int* in_sizes, int n_in,
                              void* d_out, int out_size, void* d_ws, size_t ws_size,
                              hipStream_t stream)
{
  const float* xyz  = (const float*)d_in[0];
  const float* feat = (const float*)d_in[1];
  const float* W1   = (const float*)d_in[2];
  const float* b1   = (const float*)d_in[3];
  const float* g1   = (const float*)d_in[4];
  const float* be1  = (const float*)d_in[5];
  const float* W2   = (const float*)d_in[6];
  const float* b2   = (const float*)d_in[7];
  const float* g2   = (const float*)d_in[8];
  const float* be2  = (const float*)d_in[9];
  const float* Wout = (const float*)d_in[10];
  const float* bout = (const float*)d_in[11];

  float* outp = (float*)d_out;
  float* cent = outp;                             // (B, M, 3)
  float* o    = outp + (size_t)Bn * Mn * 3;       // (B, M, 128)

  fps_kernel<<<Bn, 256, 0, stream>>>(xyz, cent);
  knn_kernel<<<Bn * Mn / 4, 256, 0, stream>>>(xyz, cent, (int*)o);
  mlp_kernel<<<Bn * Mn / 4, 256, 0, stream>>>(xyz, feat,
                                              W1, b1, g1, be1,
                                              W2, b2, g2, be2,
                                              Wout, bout, cent, o);
}